// Round 2
// baseline (555.653 us; speedup 1.0000x reference)
//
#include <hip/hip_runtime.h>

// Fused gated aggregator:
//   gates = sigmoid(nodes @ Wg + bg); data = nodes @ Wt + bt
//   out[B,D] = owner_masks(float) @ (data * gates)
// v3: 512-thread blocks (8 waves). Per-wave d-slice/b-slice halved -> Wf 32
//     regs, acc 32 regs, total ~115 VGPR -> 4 waves/SIMD (2x occupancy of v2).
//     Same 1-barrier-per-chunk pipeline, masks global->regs, dbuf nodes/vt LDS.

#define NTOT   500000
#define NBLK   512
#define NCHUNK 15625   // NTOT / 32, exact

typedef __attribute__((ext_vector_type(8))) unsigned short ushort8;
typedef __bf16 bf16x8 __attribute__((ext_vector_type(8)));
typedef __bf16 bf16x2 __attribute__((ext_vector_type(2)));
typedef __attribute__((ext_vector_type(4))) float f32x4;

// packed f32x2 -> bf16x2 (RNE; lowers to v_cvt_pk_bf16_f32)
static __device__ __forceinline__ unsigned int pkbf(float a, float b) {
  bf16x2 v;
  v[0] = (__bf16)a;
  v[1] = (__bf16)b;
  return __builtin_bit_cast(unsigned int, v);
}

// int 0/1 pair -> packed bf16 {lo,hi}; bf16(1.0) = 0x3F80. 2 cndmask + 1 or.
static __device__ __forceinline__ unsigned int mkw(int lo, int hi) {
  return (lo ? 0x3F80u : 0u) | (hi ? 0x3F800000u : 0u);
}

template <bool ATOMIC>
__global__ __launch_bounds__(512, 4)
void agg_main(const float* __restrict__ nodes, const int* __restrict__ masks,
              const float* __restrict__ Wt, const float* __restrict__ bt,
              const float* __restrict__ Wg, const float* __restrict__ bg,
              float* __restrict__ outp) {
  // double-buffered; strides padded for <=2-way bank aliasing on b128 reads
  __shared__ __align__(16) unsigned short nodes_s[2][32][136];  // [buf][node][s]
  __shared__ __align__(16) unsigned short vt_s[2][128][40];     // [buf][d][node]

  const int tid = threadIdx.x;
  const int lane = tid & 63;
  const int w = tid >> 6;    // wave 0..7
  const int q = lane >> 4;   // quad 0..3
  const int r = lane & 15;

  // ---- preload W as B-operand fragments (VGPR-resident), + biases ----
  // wave w owns d-slice [w*16, w*16+16). B-frag: n = lane&15, k = quad*8 + j
  bf16x8 Wf[2][4];  // [data/gate][ks] -- 32 VGPRs
  const int dslc = w * 16 + r;
  const float btr = bt[dslc];
  const float bgr = bg[dslc];
#pragma unroll
  for (int ks = 0; ks < 4; ++ks) {
    ushort8 ft, fg;
#pragma unroll
    for (int j = 0; j < 8; ++j) {
      const int k = ks * 32 + q * 8 + j;  // s index
      ft[j] = __builtin_bit_cast(unsigned short, (__bf16)Wt[k * 128 + dslc]);
      fg[j] = __builtin_bit_cast(unsigned short, (__bf16)Wg[k * 128 + dslc]);
    }
    Wf[0][ks] = __builtin_bit_cast(bf16x8, ft);
    Wf[1][ks] = __builtin_bit_cast(bf16x8, fg);
  }

  // pooling accumulators: wave w owns out rows [w*16, w*16+16) x ALL 128 cols
  f32x4 acc[8];  // 32 VGPRs
  const f32x4 fzero = {0.f, 0.f, 0.f, 0.f};
#pragma unroll
  for (int j = 0; j < 8; ++j) acc[j] = fzero;

  const int bid = blockIdx.x;
  const int c0 = (int)(((long long)bid * NCHUNK) / NBLK);
  const int c1 = (int)(((long long)(bid + 1) * NCHUNK) / NBLK);
  const int n = c1 - c0;

  // per-thread mask row pointer (wave w, row w*16+r, node offset q*8)
  const int* mrow = masks + (size_t)(w * 16 + r) * NTOT + q * 8;

  float4 nf[2];            // node prefetch (1 chunk deep)
  int4 miA[2], miB[2];     // mask prefetch, two named sets (static indexing)

  auto issue_nodes = [&](int c) {
    const float4* p = (const float4*)(nodes + (size_t)c * 32 * 128);
    nf[0] = p[tid];
    nf[1] = p[512 + tid];
  };

  auto issue_masks = [&](int4 (&mi)[2], int c) {
    const int k0 = c * 32;
    mi[0] = *(const int4*)(mrow + k0);
    mi[1] = *(const int4*)(mrow + k0 + 4);
  };

  auto stage = [&](int buf) {
#pragma unroll
    for (int it = 0; it < 2; ++it) {
      const int flat = it * 512 + tid;
      const int nrow = flat >> 5, nc4 = flat & 31;  // 32 rows x 32 float4
      uint2 u;
      u.x = pkbf(nf[it].x, nf[it].y);
      u.y = pkbf(nf[it].z, nf[it].w);
      *(uint2*)&nodes_s[buf][nrow][nc4 * 4] = u;
    }
  };

  // pooling: out[b][d] += mask[b][node] * V[node][d], K=32 (8 MFMA/wave)
  auto pool = [&](const int4 (&mi)[2], int buf) {
    uint4 u;
    u.x = mkw(mi[0].x, mi[0].y);
    u.y = mkw(mi[0].z, mi[0].w);
    u.z = mkw(mi[1].x, mi[1].y);
    u.w = mkw(mi[1].z, mi[1].w);
    const bf16x8 af = __builtin_bit_cast(bf16x8, u);
#pragma unroll
    for (int nt = 0; nt < 8; ++nt) {
      const bf16x8 bfr = *(const bf16x8*)&vt_s[buf][nt * 16 + r][q * 8];
      acc[nt] = __builtin_amdgcn_mfma_f32_16x16x32_bf16(af, bfr, acc[nt], 0, 0, 0);
    }
  };

  // GEMM1 [32 x 128s] @ W[128s x 16d-slice] + gated epilogue -> vt_s[buf]
  auto gemm_epi = [&](int buf) {
    f32x4 aD[2], aG[2];  // [mt]
    aD[0] = fzero; aD[1] = fzero; aG[0] = fzero; aG[1] = fzero;
#pragma unroll
    for (int ks = 0; ks < 4; ++ks) {
      // A-frag: m = lane&15 (+16*mt), k = ks*32 + quad*8 + j
      const bf16x8 a0 = *(const bf16x8*)&nodes_s[buf][r][ks * 32 + q * 8];
      const bf16x8 a1 = *(const bf16x8*)&nodes_s[buf][16 + r][ks * 32 + q * 8];
      aD[0] = __builtin_amdgcn_mfma_f32_16x16x32_bf16(a0, Wf[0][ks], aD[0], 0, 0, 0);
      aD[1] = __builtin_amdgcn_mfma_f32_16x16x32_bf16(a1, Wf[0][ks], aD[1], 0, 0, 0);
      aG[0] = __builtin_amdgcn_mfma_f32_16x16x32_bf16(a0, Wf[1][ks], aG[0], 0, 0, 0);
      aG[1] = __builtin_amdgcn_mfma_f32_16x16x32_bf16(a1, Wf[1][ks], aG[1], 0, 0, 0);
    }
    // epilogue: V = (data+bt)*sigmoid(gate+bg); write V^T[d][node]
    // C/D layout: col = lane&15, row = quad*4 + reg
#pragma unroll
    for (int mt = 0; mt < 2; ++mt) {
      float v[4];
#pragma unroll
      for (int reg = 0; reg < 4; ++reg) {
        const float x = aD[mt][reg] + btr;
        const float g = aG[mt][reg] + bgr;
        v[reg] = x * __builtin_amdgcn_rcpf(1.f + __expf(-g));
      }
      uint2 u;
      u.x = pkbf(v[0], v[1]);
      u.y = pkbf(v[2], v[3]);
      *(uint2*)&vt_s[buf][dslc][mt * 16 + q * 4] = u;
    }
  };

  int i = 0;
  // one barrier per chunk; all cross-wave hazards separated by >=1 barrier via
  // buffer parity (nodes_s/vt_s double-buffered, mask sets alternate A/B)
  auto body = [&](int buf, int4 (&mip)[2], int4 (&mii)[2]) {
    stage(buf);               // nf -> nodes_s[buf] (consumes nf)
    __syncthreads();          // drains stage writes; prefetches issued AFTER
    const int c = c0 + i;
    if (i + 1 < n) issue_nodes(c + 1);       // in flight across pool+gemm+epi
    if (i > 0) pool(mip, buf ^ 1);           // chunk c-1 (vt in other buffer)
    if (i + 1 < n) issue_masks(mii, c + 1);  // in flight across gemm+epi
    gemm_epi(buf);
    ++i;
  };

  if (n > 0) {
    issue_nodes(c0);
    issue_masks(miA, c0);  // even chunk-index -> set A
  }
  while (i < n) {
    body(0, miB, miB);              // even i: pool odd chunk (B), issue odd (B)
    if (i < n) body(1, miA, miA);   // odd  i: pool even chunk (A), issue even (A)
  }
  __syncthreads();
  if (n > 0) {
    if ((n - 1) & 1) pool(miB, 1);
    else             pool(miA, 0);
  }

  // ---- write per-block partial (or atomic accumulate) ----
#pragma unroll
  for (int nt = 0; nt < 8; ++nt)
#pragma unroll
    for (int reg = 0; reg < 4; ++reg) {
      const int b = w * 16 + q * 4 + reg;
      const int d = nt * 16 + r;
      if (ATOMIC)
        atomicAdd(&outp[b * 128 + d], acc[nt][reg]);
      else
        outp[(size_t)bid * 16384 + b * 128 + d] = acc[nt][reg];
    }
}

__global__ __launch_bounds__(256)
void agg_reduce(const float* __restrict__ part, float* __restrict__ out) {
  // 512 blocks x 256 thr = 131072 = 8 groups x 16384 outputs; 64 partials each
  const int gid = blockIdx.x * 256 + threadIdx.x;
  const int i = gid & 16383;
  const int grp = gid >> 14;
  const float* p = part + (size_t)grp * 64 * 16384 + i;
  float s = 0.f;
#pragma unroll 8
  for (int g = 0; g < 64; ++g) s += p[(size_t)g * 16384];
  atomicAdd(&out[i], s);
}

extern "C" void kernel_launch(void* const* d_in, const int* in_sizes, int n_in,
                              void* d_out, int out_size, void* d_ws, size_t ws_size,
                              hipStream_t stream) {
  const float* nodes = (const float*)d_in[0];
  const int*   masks = (const int*)d_in[1];
  const float* Wt    = (const float*)d_in[2];
  const float* bt    = (const float*)d_in[3];
  const float* Wg    = (const float*)d_in[4];
  const float* bg    = (const float*)d_in[5];
  float* out = (float*)d_out;

  hipMemsetAsync(d_out, 0, (size_t)out_size * sizeof(float), stream);

  const size_t need = (size_t)NBLK * 16384 * sizeof(float);
  if (ws_size >= need) {
    agg_main<false><<<NBLK, 512, 0, stream>>>(nodes, masks, Wt, bt, Wg, bg, (float*)d_ws);
    agg_reduce<<<512, 256, 0, stream>>>((const float*)d_ws, out);
  } else {
    agg_main<true><<<NBLK, 512, 0, stream>>>(nodes, masks, Wt, bt, Wg, bg, out);
  }
}

// Round 3
// 517.467 us; speedup vs baseline: 1.0738x; 1.0738x over previous
//
#include <hip/hip_runtime.h>

// Fused gated aggregator:
//   gates = sigmoid(nodes @ Wg + bg); data = nodes @ Wt + bt
//   out[B,D] = owner_masks(float) @ (data * gates)
// v4: 512-thread blocks (8 waves, 2 blocks/CU). Spill fix vs v3: single mask
//     set (convert-then-reissue), 32-bit offset addressing, arch-VGPR diet.
//     Same 1-barrier-per-chunk pipeline, dbuf nodes/vt LDS.

#define NTOT   500000
#define NBLK   512
#define NCHUNK 15625   // NTOT / 32, exact

typedef __attribute__((ext_vector_type(8))) unsigned short ushort8;
typedef __bf16 bf16x8 __attribute__((ext_vector_type(8)));
typedef __bf16 bf16x2 __attribute__((ext_vector_type(2)));
typedef __attribute__((ext_vector_type(4))) float f32x4;

// packed f32x2 -> bf16x2 (RNE; lowers to v_cvt_pk_bf16_f32)
static __device__ __forceinline__ unsigned int pkbf(float a, float b) {
  bf16x2 v;
  v[0] = (__bf16)a;
  v[1] = (__bf16)b;
  return __builtin_bit_cast(unsigned int, v);
}

// int 0/1 pair -> packed bf16 {lo,hi}; bf16(1.0) = 0x3F80. 2 cndmask + 1 or.
static __device__ __forceinline__ unsigned int mkw(int lo, int hi) {
  return (lo ? 0x3F80u : 0u) | (hi ? 0x3F800000u : 0u);
}

template <bool ATOMIC>
__global__ __launch_bounds__(512, 4)
void agg_main(const float* __restrict__ nodes, const int* __restrict__ masks,
              const float* __restrict__ Wt, const float* __restrict__ bt,
              const float* __restrict__ Wg, const float* __restrict__ bg,
              float* __restrict__ outp) {
  // double-buffered; strides padded for <=2-way bank aliasing on b128 reads
  __shared__ __align__(16) unsigned short nodes_s[2][32][136];  // [buf][node][s]
  __shared__ __align__(16) unsigned short vt_s[2][128][40];     // [buf][d][node]

  const int tid = threadIdx.x;
  const int lane = tid & 63;
  const int w = tid >> 6;    // wave 0..7
  const int q = lane >> 4;   // quad 0..3
  const int r = lane & 15;

  // ---- preload W as B-operand fragments (reg-resident), + biases ----
  // wave w owns d-slice [w*16, w*16+16). B-frag: n = lane&15, k = quad*8 + j
  bf16x8 Wf[2][4];  // [data/gate][ks] -- 32 regs
  const int dslc = w * 16 + r;
  const float btr = bt[dslc];
  const float bgr = bg[dslc];
#pragma unroll
  for (int ks = 0; ks < 4; ++ks) {
    ushort8 ft, fg;
#pragma unroll
    for (int j = 0; j < 8; ++j) {
      const int k = ks * 32 + q * 8 + j;  // s index
      ft[j] = __builtin_bit_cast(unsigned short, (__bf16)Wt[k * 128 + dslc]);
      fg[j] = __builtin_bit_cast(unsigned short, (__bf16)Wg[k * 128 + dslc]);
    }
    Wf[0][ks] = __builtin_bit_cast(bf16x8, ft);
    Wf[1][ks] = __builtin_bit_cast(bf16x8, fg);
  }

  // pooling accumulators: wave w owns out rows [w*16, w*16+16) x ALL 128 cols
  f32x4 acc[8];  // 32 regs (acc-file)
  const f32x4 fzero = {0.f, 0.f, 0.f, 0.f};
#pragma unroll
  for (int j = 0; j < 8; ++j) acc[j] = fzero;

  const int bid = blockIdx.x;
  const int c0 = (int)(((long long)bid * NCHUNK) / NBLK);
  const int c1 = (int)(((long long)(bid + 1) * NCHUNK) / NBLK);
  const int n = c1 - c0;

  // 32-bit mask offset (masks buffer = 256 MB < 2^31 elements*4B)
  const unsigned moff = (unsigned)(w * 16 + r) * (unsigned)NTOT + (unsigned)(q * 8);

  float4 nf[2];   // node prefetch (1 chunk deep)
  int4 mi[2];     // mask prefetch (single set, convert-then-reissue)

  auto issue_nodes = [&](int c) {
    const float4* p = (const float4*)nodes;
    const int base = c * 1024 + tid;   // 32-bit index, max ~16M
    nf[0] = p[base];
    nf[1] = p[base + 512];
  };

  auto issue_masks = [&](int c) {
    const unsigned o = moff + (unsigned)c * 32u;
    mi[0] = *(const int4*)(masks + o);
    mi[1] = *(const int4*)(masks + o + 4);
  };

  auto stage = [&](int buf) {
#pragma unroll
    for (int it = 0; it < 2; ++it) {
      const int flat = it * 512 + tid;
      const int nrow = flat >> 5, nc4 = flat & 31;  // 32 rows x 32 float4
      uint2 u;
      u.x = pkbf(nf[it].x, nf[it].y);
      u.y = pkbf(nf[it].z, nf[it].w);
      *(uint2*)&nodes_s[buf][nrow][nc4 * 4] = u;
    }
  };

  // pooling: out[b][d] += mask[b][node] * V[node][d], K=32 (8 MFMA/wave).
  // Converts mi -> packed bf16 first, then reissues mi for chunk cnext
  // (in flight across gemm + stage + barrier of the next body).
  auto pool_reissue = [&](int buf, int cnext) {
    uint4 u;
    u.x = mkw(mi[0].x, mi[0].y);
    u.y = mkw(mi[0].z, mi[0].w);
    u.z = mkw(mi[1].x, mi[1].y);
    u.w = mkw(mi[1].z, mi[1].w);
    issue_masks(cnext);
    const bf16x8 af = __builtin_bit_cast(bf16x8, u);
#pragma unroll
    for (int nt = 0; nt < 8; ++nt) {
      const bf16x8 bfr = *(const bf16x8*)&vt_s[buf][nt * 16 + r][q * 8];
      acc[nt] = __builtin_amdgcn_mfma_f32_16x16x32_bf16(af, bfr, acc[nt], 0, 0, 0);
    }
  };

  auto pool_last = [&](int buf) {
    uint4 u;
    u.x = mkw(mi[0].x, mi[0].y);
    u.y = mkw(mi[0].z, mi[0].w);
    u.z = mkw(mi[1].x, mi[1].y);
    u.w = mkw(mi[1].z, mi[1].w);
    const bf16x8 af = __builtin_bit_cast(bf16x8, u);
#pragma unroll
    for (int nt = 0; nt < 8; ++nt) {
      const bf16x8 bfr = *(const bf16x8*)&vt_s[buf][nt * 16 + r][q * 8];
      acc[nt] = __builtin_amdgcn_mfma_f32_16x16x32_bf16(af, bfr, acc[nt], 0, 0, 0);
    }
  };

  // GEMM1 [32 x 128s] @ W[128s x 16d-slice] + gated epilogue -> vt_s[buf]
  auto gemm_epi = [&](int buf) {
    f32x4 aD[2], aG[2];  // [mt]
    aD[0] = fzero; aD[1] = fzero; aG[0] = fzero; aG[1] = fzero;
#pragma unroll
    for (int ks = 0; ks < 4; ++ks) {
      // A-frag: m = lane&15 (+16*mt), k = ks*32 + quad*8 + j
      const bf16x8 a0 = *(const bf16x8*)&nodes_s[buf][r][ks * 32 + q * 8];
      const bf16x8 a1 = *(const bf16x8*)&nodes_s[buf][16 + r][ks * 32 + q * 8];
      aD[0] = __builtin_amdgcn_mfma_f32_16x16x32_bf16(a0, Wf[0][ks], aD[0], 0, 0, 0);
      aD[1] = __builtin_amdgcn_mfma_f32_16x16x32_bf16(a1, Wf[0][ks], aD[1], 0, 0, 0);
      aG[0] = __builtin_amdgcn_mfma_f32_16x16x32_bf16(a0, Wf[1][ks], aG[0], 0, 0, 0);
      aG[1] = __builtin_amdgcn_mfma_f32_16x16x32_bf16(a1, Wf[1][ks], aG[1], 0, 0, 0);
    }
    // epilogue: V = (data+bt)*sigmoid(gate+bg); write V^T[d][node]
    // C/D layout: col = lane&15, row = quad*4 + reg
#pragma unroll
    for (int mt = 0; mt < 2; ++mt) {
      float v[4];
#pragma unroll
      for (int reg = 0; reg < 4; ++reg) {
        const float x = aD[mt][reg] + btr;
        const float g = aG[mt][reg] + bgr;
        v[reg] = x * __builtin_amdgcn_rcpf(1.f + __expf(-g));
      }
      uint2 u;
      u.x = pkbf(v[0], v[1]);
      u.y = pkbf(v[2], v[3]);
      *(uint2*)&vt_s[buf][dslc][mt * 16 + q * 4] = u;
    }
  };

  int i = 0;
  // one barrier per chunk; all cross-wave hazards separated by >=1 barrier via
  // buffer parity (nodes_s/vt_s double-buffered)
  auto body = [&](int buf) {
    stage(buf);               // nf -> nodes_s[buf] (consumes nf)
    __syncthreads();          // drains stage writes; prefetches issued AFTER
    const int c = c0 + i;
    if (i + 1 < n) issue_nodes(c + 1);     // in flight across pool+gemm+epi
    if (i > 0) pool_reissue(buf ^ 1, c);   // pool chunk c-1; reissue mi <- c
    gemm_epi(buf);
    ++i;
  };

  if (n > 0) {
    issue_nodes(c0);
    issue_masks(c0);
  }
  while (i < n) {
    body(0);             // even i
    if (i < n) body(1);  // odd i
  }
  __syncthreads();
  if (n > 0) pool_last((n - 1) & 1);  // mi holds chunk n-1

  // ---- write per-block partial (or atomic accumulate) ----
#pragma unroll
  for (int nt = 0; nt < 8; ++nt)
#pragma unroll
    for (int reg = 0; reg < 4; ++reg) {
      const int b = w * 16 + q * 4 + reg;
      const int d = nt * 16 + r;
      if (ATOMIC)
        atomicAdd(&outp[b * 128 + d], acc[nt][reg]);
      else
        outp[(size_t)bid * 16384 + b * 128 + d] = acc[nt][reg];
    }
}

__global__ __launch_bounds__(256)
void agg_reduce(const float* __restrict__ part, float* __restrict__ out) {
  // 128 blocks x 256 thr = 32768 = 8 groups x 4096 float4 outputs; 64 partials each
  const int gid = blockIdx.x * 256 + threadIdx.x;
  const int i4 = gid & 4095;
  const int grp = gid >> 12;
  const float4* p = (const float4*)part + (size_t)grp * 64 * 4096 + i4;
  float4 s = {0.f, 0.f, 0.f, 0.f};
#pragma unroll 8
  for (int g = 0; g < 64; ++g) {
    const float4 v = p[(size_t)g * 4096];
    s.x += v.x; s.y += v.y; s.z += v.z; s.w += v.w;
  }
  atomicAdd(&out[i4 * 4 + 0], s.x);
  atomicAdd(&out[i4 * 4 + 1], s.y);
  atomicAdd(&out[i4 * 4 + 2], s.z);
  atomicAdd(&out[i4 * 4 + 3], s.w);
}

extern "C" void kernel_launch(void* const* d_in, const int* in_sizes, int n_in,
                              void* d_out, int out_size, void* d_ws, size_t ws_size,
                              hipStream_t stream) {
  const float* nodes = (const float*)d_in[0];
  const int*   masks = (const int*)d_in[1];
  const float* Wt    = (const float*)d_in[2];
  const float* bt    = (const float*)d_in[3];
  const float* Wg    = (const float*)d_in[4];
  const float* bg    = (const float*)d_in[5];
  float* out = (float*)d_out;

  hipMemsetAsync(d_out, 0, (size_t)out_size * sizeof(float), stream);

  const size_t need = (size_t)NBLK * 16384 * sizeof(float);
  if (ws_size >= need) {
    agg_main<false><<<NBLK, 512, 0, stream>>>(nodes, masks, Wt, bt, Wg, bg, (float*)d_ws);
    agg_reduce<<<128, 256, 0, stream>>>((const float*)d_ws, out);
  } else {
    agg_main<true><<<NBLK, 512, 0, stream>>>(nodes, masks, Wt, bt, Wg, bg, out);
  }
}